// Round 2
// baseline (1427.405 us; speedup 1.0000x reference)
//
#include <hip/hip_runtime.h>
#include <hip/hip_bf16.h>

typedef __bf16 bf16x8 __attribute__((ext_vector_type(8)));
typedef float floatx4 __attribute__((ext_vector_type(4)));
typedef unsigned short ushort_t;
typedef ushort_t ushort8 __attribute__((ext_vector_type(8)));

#define KD 768   // d_model = inner K of both GEMMs

// ---------------------------------------------------------------------------
// transpose + convert: dst[n][k] = bf16(src[k][n]), 768x768
// ---------------------------------------------------------------------------
__global__ __launch_bounds__(256) void transpose_cvt_kernel(
    const float* __restrict__ src, __hip_bfloat16* __restrict__ dst) {
  __shared__ float tile[32][33];
  const int bx = blockIdx.x % 24;  // src col tile
  const int by = blockIdx.x / 24;  // src row tile
  const int tx = threadIdx.x & 31;
  const int ty = threadIdx.x >> 5;
#pragma unroll
  for (int i = 0; i < 32; i += 8)
    tile[ty + i][tx] = src[(size_t)(by * 32 + ty + i) * KD + bx * 32 + tx];
  __syncthreads();
#pragma unroll
  for (int i = 0; i < 32; i += 8)
    dst[(size_t)(bx * 32 + ty + i) * KD + by * 32 + tx] =
        __float2bfloat16(tile[tx][ty + i]);
}

// ---------------------------------------------------------------------------
// Conv / patch embedding. Circular patch ring (&127); patch 127 uses the
// edge pad (elements 8..15 = x[1023]). Round-2 change: buffer-role rotation
// (unroll by 4) halves the patch loads; FP accumulation order unchanged.
// ---------------------------------------------------------------------------
__device__ __forceinline__ void load_patch(const float* __restrict__ xr,
                                           int qw, float* b) {
  if (qw < 127) {
    const float4* p4 = (const float4*)(xr + qw * 8);
    float4 v0 = p4[0], v1 = p4[1], v2 = p4[2], v3 = p4[3];
    b[0] = v0.x; b[1] = v0.y; b[2] = v0.z; b[3] = v0.w;
    b[4] = v1.x; b[5] = v1.y; b[6] = v1.z; b[7] = v1.w;
    b[8] = v2.x; b[9] = v2.y; b[10] = v2.z; b[11] = v2.w;
    b[12] = v3.x; b[13] = v3.y; b[14] = v3.z; b[15] = v3.w;
  } else {
    float4 v0 = *(const float4*)(xr + 1016);
    float4 v1 = *(const float4*)(xr + 1020);
    b[0] = v0.x; b[1] = v0.y; b[2] = v0.z; b[3] = v0.w;
    b[4] = v1.x; b[5] = v1.y; b[6] = v1.z; b[7] = v1.w;
    float e = v1.w;  // x[1023], edge value
#pragma unroll
    for (int i = 8; i < 16; ++i) b[i] = e;
  }
}

__global__ __launch_bounds__(256) void conv_kernel(
    const float* __restrict__ x, const float* __restrict__ cw,
    __hip_bfloat16* __restrict__ emb, int nb) {
  const int lb = blockIdx.x;       // chunk-local series index
  const int n = nb + lb;           // global series index (b*21+c)
  const float* xr = x + (size_t)n * 1024;
  const int o = blockIdx.y * 256 + threadIdx.x;

  float w[48];
  const float4* wp = (const float4*)(cw + (size_t)o * 48);
#pragma unroll
  for (int q = 0; q < 12; ++q) {
    float4 v = wp[q];
    w[q * 4 + 0] = v.x; w[q * 4 + 1] = v.y;
    w[q * 4 + 2] = v.z; w[q * 4 + 3] = v.w;
  }

  __hip_bfloat16* erow = emb + (size_t)lb * 128 * KD + o;
  float P0[16], P1[16], P2[16], P3[16];

  // pair(out p) uses windows (Pa=q(p-1), Pb=q(p), Pc=q(p+1), Pd=q(p+2))
  auto pair = [&](const float* Pa, const float* Pb, const float* Pc,
                  const float* Pd, int p) {
    float a0 = 0.f, a1 = 0.f;
#pragma unroll
    for (int i = 0; i < 16; ++i) {
      a0 += w[i * 3 + 0] * Pa[i];
      a0 += w[i * 3 + 1] * Pb[i];
      a0 += w[i * 3 + 2] * Pc[i];
      a1 += w[i * 3 + 0] * Pb[i];
      a1 += w[i * 3 + 1] * Pc[i];
      a1 += w[i * 3 + 2] * Pd[i];
    }
    erow[(size_t)p * KD] = __float2bfloat16(a0);
    erow[(size_t)(p + 1) * KD] = __float2bfloat16(a1);
  };

  load_patch(xr, 127, P0);  // q = -1 (circular)
  load_patch(xr, 0, P1);
  for (int p = 0; p < 128; p += 4) {
    load_patch(xr, p + 1, P2);
    load_patch(xr, (p + 2) & 127, P3);
    pair(P0, P1, P2, P3, p);            // outputs p, p+1
    load_patch(xr, (p + 3) & 127, P0);  // becomes q = p+3
    load_patch(xr, (p + 4) & 127, P1);  // becomes q = p+4
    pair(P2, P3, P0, P1, p + 2);        // outputs p+2, p+3
  }
}

// ---------------------------------------------------------------------------
// bf16 MFMA GEMM, 256x256 tile / BK=32 / 8 waves (2M x 4N), 512 threads.
// 4-slot LDS ring per operand (4 x 256 x 32 bf16 = 64 KiB each, 128 KiB tot).
// One barrier per K-tile; stage for tile t+3 issued right after the barrier,
// overwriting the slot consumed at tile t-1 (3-tile-deep pipeline, ~3700 cyc
// of latency cover). Counted vmcnt(8) in steady state (never 0 until tail).
// Safety: each wave drains its OWN ds_reads (lgkmcnt 0) and its OWN tile-t
// loads (vmcnt<=8) before the shared barrier, so after the barrier slot t is
// fully populated for all waves and slot t-1 is fully consumed.
// BK=32: a fragment's LDS read covers a dense contiguous 1 KiB (16 rows x
// 64 B) -> conflict-free without swizzle; LDS layout is plain row-major and
// global_load_lds dest is linear (lane*16B).
// Grid: flat mt*3 blocks; XCD-chunked bijective remap, n-tile fastest so the
// 3 blocks sharing an A panel run consecutively on one XCD (L2 reuse).
// MODE 1: out = bf16(relu(acc + bias))          (hidden, bf16*)
// MODE 2: out = float(emb) + acc + bias         (final,  float*)
// ---------------------------------------------------------------------------
template <int MODE>
__global__ __launch_bounds__(512, 2) void gemm_kernel(
    const __hip_bfloat16* __restrict__ A, const __hip_bfloat16* __restrict__ Bt,
    const float* __restrict__ bias, const __hip_bfloat16* __restrict__ emb,
    void* __restrict__ outp, int mt) {
  __shared__ __align__(16) ushort_t As[4 * 256 * 32];  // 64 KiB ring
  __shared__ __align__(16) ushort_t Bs[4 * 256 * 32];  // 64 KiB ring
  const int tid = threadIdx.x;
  const int lane = tid & 63;
  const int w = __builtin_amdgcn_readfirstlane(tid >> 6);  // wave id 0..7

  // ---- XCD-chunked bijective remap (m204), n fastest within a chunk ----
  const int total = mt * 3;
  const int q = total >> 3, r = total & 7;
  const int xcd = blockIdx.x & 7;
  const int j8 = blockIdx.x >> 3;
  const int wg =
      (xcd < r ? xcd * (q + 1) : r * (q + 1) + (xcd - r) * q) + j8;
  const int m0 = (wg / 3) * 256;
  const int n0 = (wg % 3) * 256;

  // ---- staging addresses. Wave w stages rows w*32..w*32+31 of A and B:
  // 2 instrs per operand per K-tile (each = 16 rows x 64 B, linear dest).
  const int sr4 = lane >> 2;           // row within 16-row slab
  const int sc4 = lane & 3;            // 16B chunk within 64B row
  const size_t ga = (size_t)(m0 + w * 32 + sr4) * KD + sc4 * 8;
  const size_t gb = (size_t)(n0 + w * 32 + sr4) * KD + sc4 * 8;
  typedef __attribute__((address_space(3))) void lv_t;
  typedef __attribute__((address_space(1))) const void gv_t;
  char* asb = (char*)&As[0] + w * 2048;  // wave's 32-row slab (bytes)
  char* bsb = (char*)&Bs[0] + w * 2048;

  auto stage = [&](int t) {
    const int kt = t * 32;
    const int sb = (t & 3) * 16384;     // slot byte offset
    __builtin_amdgcn_global_load_lds((gv_t*)(A + ga + kt),
                                     (lv_t*)(asb + sb), 16, 0, 0);
    __builtin_amdgcn_global_load_lds((gv_t*)(A + ga + kt + (size_t)16 * KD),
                                     (lv_t*)(asb + sb + 1024), 16, 0, 0);
    __builtin_amdgcn_global_load_lds((gv_t*)(Bt + gb + kt),
                                     (lv_t*)(bsb + sb), 16, 0, 0);
    __builtin_amdgcn_global_load_lds((gv_t*)(Bt + gb + kt + (size_t)16 * KD),
                                     (lv_t*)(bsb + sb + 1024), 16, 0, 0);
  };

  // ---- compute-side LDS offsets (row-major, no swizzle needed at BK=32) --
  const int rl = lane & 15;            // fragment row/col within 16
  const int ql = lane >> 4;            // k sub-chunk 0..3
  const int wm = (w >> 2) * 128;       // wave M offset
  const int wn = (w & 3) * 64;         // wave N offset
  const int ea = (wm + rl) * 32 + ql * 8;  // ushort idx within slot
  const int eb = (wn + rl) * 32 + ql * 8;

  floatx4 acc[8][4];
#pragma unroll
  for (int mi = 0; mi < 8; ++mi)
#pragma unroll
    for (int nj = 0; nj < 4; ++nj) acc[mi][nj] = (floatx4){0.f, 0.f, 0.f, 0.f};

  // ---- main loop: 24 K-tiles, ring-4, one barrier per tile ----
  stage(0);
  stage(1);
  stage(2);
  for (int t = 0; t < 24; ++t) {
    // Drain own ds_reads of tile t-1 and own loads of tile t; rendezvous.
    // In flight after wait: tiles t+1, t+2 (8 loads) in steady state.
    if (t < 22)
      asm volatile("s_waitcnt lgkmcnt(0)\n\ts_waitcnt vmcnt(8)\n\ts_barrier"
                   ::: "memory");
    else if (t == 22)
      asm volatile("s_waitcnt lgkmcnt(0)\n\ts_waitcnt vmcnt(4)\n\ts_barrier"
                   ::: "memory");
    else
      asm volatile("s_waitcnt lgkmcnt(0)\n\ts_waitcnt vmcnt(0)\n\ts_barrier"
                   ::: "memory");
    if (t < 21) stage(t + 3);  // overwrites slot consumed at tile t-1

    const ushort_t* Ab = &As[(t & 3) * 8192];
    const ushort_t* Bb = &Bs[(t & 3) * 8192];
    bf16x8 av[8], bv[4];
#pragma unroll
    for (int mi = 0; mi < 8; ++mi)
      av[mi] = __builtin_bit_cast(bf16x8, *(const ushort8*)&Ab[ea + mi * 512]);
#pragma unroll
    for (int nj = 0; nj < 4; ++nj)
      bv[nj] = __builtin_bit_cast(bf16x8, *(const ushort8*)&Bb[eb + nj * 512]);
    __builtin_amdgcn_s_setprio(1);
#pragma unroll
    for (int mi = 0; mi < 8; ++mi)
#pragma unroll
      for (int nj = 0; nj < 4; ++nj)
        acc[mi][nj] = __builtin_amdgcn_mfma_f32_16x16x32_bf16(
            av[mi], bv[nj], acc[mi][nj], 0, 0, 0);
    __builtin_amdgcn_s_setprio(0);
  }

  // ---- epilogue: D[row=(lane>>4)*4+p][col=lane&15] per 16x16 fragment ----
#pragma unroll
  for (int nj = 0; nj < 4; ++nj) {
    const int cc = n0 + wn + nj * 16 + rl;
    const float bvs = bias[cc];
#pragma unroll
    for (int mi = 0; mi < 8; ++mi) {
      const int rbase = m0 + wm + mi * 16 + ql * 4;
#pragma unroll
      for (int p = 0; p < 4; ++p) {
        float v = acc[mi][nj][p] + bvs;
        if (MODE == 1) {
          v = v > 0.f ? v : 0.f;
          ((__hip_bfloat16*)outp)[(size_t)(rbase + p) * KD + cc] =
              __float2bfloat16(v);
        } else {
          v += __bfloat162float(emb[(size_t)(rbase + p) * KD + cc]);
          ((float*)outp)[(size_t)(rbase + p) * KD + cc] = v;
        }
      }
    }
  }
}

// ---------------------------------------------------------------------------
extern "C" void kernel_launch(void* const* d_in, const int* in_sizes, int n_in,
                              void* d_out, int out_size, void* d_ws,
                              size_t ws_size, hipStream_t stream) {
  const float* x = (const float*)d_in[0];
  const float* cw = (const float*)d_in[1];
  const float* w1 = (const float*)d_in[2];
  const float* b1 = (const float*)d_in[3];
  const float* w2 = (const float*)d_in[4];
  const float* b2 = (const float*)d_in[5];
  // d_in[6] = reverse flag, unused by the reference computation.
  float* out = (float*)d_out;

  // Chunk the 1344 (b,c) series so emb/hidden bf16 intermediates fit d_ws
  // (and stay L3-resident). NC=4 -> ~134 MB of workspace; cn even so cn*128
  // is a multiple of 256 (GEMM BM).
  int NC = 4;
  while (NC < 32) {
    size_t cn_ = 1344 / NC;
    size_t need = 2 * (size_t)KD * KD * 2 + 2 * cn_ * 128 * KD * 2;
    if (need <= ws_size) break;
    NC *= 2;
  }
  const int cn = 1344 / NC;
  const int mt = cn / 2;  // 256-row M tiles per chunk

  __hip_bfloat16* w1t = (__hip_bfloat16*)d_ws;
  __hip_bfloat16* w2t = w1t + (size_t)KD * KD;
  __hip_bfloat16* embc = w2t + (size_t)KD * KD;
  __hip_bfloat16* hidc = embc + (size_t)cn * 128 * KD;

  transpose_cvt_kernel<<<576, 256, 0, stream>>>(w1, w1t);
  transpose_cvt_kernel<<<576, 256, 0, stream>>>(w2, w2t);

  for (int c = 0; c < NC; ++c) {
    const int nb = c * cn;
    conv_kernel<<<dim3(cn, 3), 256, 0, stream>>>(x, cw, embc, nb);
    gemm_kernel<1><<<dim3(mt * 3), 512, 0, stream>>>(embc, w1t, b1, nullptr,
                                                     (void*)hidc, mt);
    gemm_kernel<2><<<dim3(mt * 3), 512, 0, stream>>>(
        hidc, w2t, b2, embc, (void*)(out + (size_t)nb * 128 * KD), mt);
  }
}

// Round 3
// 1254.508 us; speedup vs baseline: 1.1378x; 1.1378x over previous
//
#include <hip/hip_runtime.h>
#include <hip/hip_bf16.h>

typedef __bf16 bf16x8 __attribute__((ext_vector_type(8)));
typedef float floatx4 __attribute__((ext_vector_type(4)));
typedef unsigned short ushort_t;
typedef ushort_t ushort8 __attribute__((ext_vector_type(8)));

#define KD 768   // d_model = inner K of both GEMMs

// ---------------------------------------------------------------------------
// transpose + convert: dst[n][k] = bf16(src[k][n]), 768x768
// ---------------------------------------------------------------------------
__global__ __launch_bounds__(256) void transpose_cvt_kernel(
    const float* __restrict__ src, __hip_bfloat16* __restrict__ dst) {
  __shared__ float tile[32][33];
  const int bx = blockIdx.x % 24;  // src col tile
  const int by = blockIdx.x / 24;  // src row tile
  const int tx = threadIdx.x & 31;
  const int ty = threadIdx.x >> 5;
#pragma unroll
  for (int i = 0; i < 32; i += 8)
    tile[ty + i][tx] = src[(size_t)(by * 32 + ty + i) * KD + bx * 32 + tx];
  __syncthreads();
#pragma unroll
  for (int i = 0; i < 32; i += 8)
    dst[(size_t)(bx * 32 + ty + i) * KD + by * 32 + tx] =
        __float2bfloat16(tile[tx][ty + i]);
}

// ---------------------------------------------------------------------------
// Conv / patch embedding (unchanged from round 2; passed correctness).
// ---------------------------------------------------------------------------
__device__ __forceinline__ void load_patch(const float* __restrict__ xr,
                                           int qw, float* b) {
  if (qw < 127) {
    const float4* p4 = (const float4*)(xr + qw * 8);
    float4 v0 = p4[0], v1 = p4[1], v2 = p4[2], v3 = p4[3];
    b[0] = v0.x; b[1] = v0.y; b[2] = v0.z; b[3] = v0.w;
    b[4] = v1.x; b[5] = v1.y; b[6] = v1.z; b[7] = v1.w;
    b[8] = v2.x; b[9] = v2.y; b[10] = v2.z; b[11] = v2.w;
    b[12] = v3.x; b[13] = v3.y; b[14] = v3.z; b[15] = v3.w;
  } else {
    float4 v0 = *(const float4*)(xr + 1016);
    float4 v1 = *(const float4*)(xr + 1020);
    b[0] = v0.x; b[1] = v0.y; b[2] = v0.z; b[3] = v0.w;
    b[4] = v1.x; b[5] = v1.y; b[6] = v1.z; b[7] = v1.w;
    float e = v1.w;  // x[1023], edge value
#pragma unroll
    for (int i = 8; i < 16; ++i) b[i] = e;
  }
}

__global__ __launch_bounds__(256) void conv_kernel(
    const float* __restrict__ x, const float* __restrict__ cw,
    __hip_bfloat16* __restrict__ emb, int nb) {
  const int lb = blockIdx.x;       // chunk-local series index
  const int n = nb + lb;           // global series index (b*21+c)
  const float* xr = x + (size_t)n * 1024;
  const int o = blockIdx.y * 256 + threadIdx.x;

  float w[48];
  const float4* wp = (const float4*)(cw + (size_t)o * 48);
#pragma unroll
  for (int q = 0; q < 12; ++q) {
    float4 v = wp[q];
    w[q * 4 + 0] = v.x; w[q * 4 + 1] = v.y;
    w[q * 4 + 2] = v.z; w[q * 4 + 3] = v.w;
  }

  __hip_bfloat16* erow = emb + (size_t)lb * 128 * KD + o;
  float P0[16], P1[16], P2[16], P3[16];

  auto pair = [&](const float* Pa, const float* Pb, const float* Pc,
                  const float* Pd, int p) {
    float a0 = 0.f, a1 = 0.f;
#pragma unroll
    for (int i = 0; i < 16; ++i) {
      a0 += w[i * 3 + 0] * Pa[i];
      a0 += w[i * 3 + 1] * Pb[i];
      a0 += w[i * 3 + 2] * Pc[i];
      a1 += w[i * 3 + 0] * Pb[i];
      a1 += w[i * 3 + 1] * Pc[i];
      a1 += w[i * 3 + 2] * Pd[i];
    }
    erow[(size_t)p * KD] = __float2bfloat16(a0);
    erow[(size_t)(p + 1) * KD] = __float2bfloat16(a1);
  };

  load_patch(xr, 127, P0);  // q = -1 (circular)
  load_patch(xr, 0, P1);
  for (int p = 0; p < 128; p += 4) {
    load_patch(xr, p + 1, P2);
    load_patch(xr, (p + 2) & 127, P3);
    pair(P0, P1, P2, P3, p);
    load_patch(xr, (p + 3) & 127, P0);
    load_patch(xr, (p + 4) & 127, P1);
    pair(P2, P3, P0, P1, p + 2);
  }
}

// ---------------------------------------------------------------------------
// bf16 MFMA GEMM, BM=256 / BN=128 / BK=64, 8 waves (4M x 2N), 512 threads.
// Each wave owns 64x64 C = 4x4 fragments of 16x16x32 MFMA.
// LDS ring-3: A 3x(256x64) = 96 KiB, B 3x(128x64) = 48 KiB (144 KiB total).
// Rows are 128 B (8 chunks of 16 B); chunk q of row r stored at slot
// q ^ (r&7): a wave ds_read_b128 fragment hits granule q^(rl&7) -> each of
// 8 slots x2 lanes = beat-conflict-free (round-1-proven swizzle).
// global_load_lds dest is linear (wave base + lane*16); swizzle applied by
// inverse-permuting the per-lane GLOBAL source (both-sides rule).
// Schedule (T3+T4+T5): per K-tile, 2 phases (ks split). Each phase:
//   {8x ds_read, 3x global_load_lds for tile t+2} -> barrier ->
//   setprio(1) + 16 MFMA + setprio(0) -> barrier.
// Counted gate: vmcnt(6) folded into phase-1's pre-MFMA barrier drains tile
// t+1's 6 loads, leaves tile t+2's 6 in flight (never 0 until tail).
// Race-safety: stage for t+2 overwrites ring slot last read at tile t-1,
// whose ds_reads drained before the inter-tile barrier; gates are per-wave
// counted vmcnt + barrier (all waves gated => all loads landed).
// MODE 1: out = bf16(relu(acc + bias))          (hidden, bf16*)
// MODE 2: out = float(emb) + acc + bias         (final,  float*)
// ---------------------------------------------------------------------------
template <int MODE>
__global__ __launch_bounds__(512, 2) void gemm_kernel(
    const __hip_bfloat16* __restrict__ A, const __hip_bfloat16* __restrict__ Bt,
    const float* __restrict__ bias, const __hip_bfloat16* __restrict__ emb,
    void* __restrict__ outp, int mt) {
  __shared__ __align__(16) ushort_t As[3 * 256 * 64];  // 96 KiB ring-3
  __shared__ __align__(16) ushort_t Bs[3 * 128 * 64];  // 48 KiB ring-3
  const int tid = threadIdx.x;
  const int lane = tid & 63;
  const int w = __builtin_amdgcn_readfirstlane(tid >> 6);  // wave id 0..7

  // ---- XCD-chunked bijective remap (m204), n fastest within a chunk ----
  const int total = mt * 6;
  const int q8 = total >> 3, r8 = total & 7;
  const int xcd = blockIdx.x & 7;
  const int j8 = blockIdx.x >> 3;
  const int wg =
      (xcd < r8 ? xcd * (q8 + 1) : r8 * (q8 + 1) + (xcd - r8) * q8) + j8;
  const int m0 = (wg / 6) * 256;
  const int n0 = (wg % 6) * 128;

  // ---- staging (block-wide: one load = 512 threads x 16B = 64 rows) ----
  const int srow = tid >> 3;                 // row 0..63 within a 64-row part
  const int schunk = (tid & 7) ^ (srow & 7); // inverse-swizzled source chunk
  const size_t ga = (size_t)(m0 + srow) * KD + schunk * 8;
  const size_t gb = (size_t)(n0 + srow) * KD + schunk * 8;
  typedef __attribute__((address_space(3))) void lv_t;
  typedef __attribute__((address_space(1))) const void gv_t;
  const int dw = w * 1024;  // wave-uniform dest base within an 8 KiB part

  auto stageA = [&](int t, int r3, int i) {
    __builtin_amdgcn_global_load_lds(
        (gv_t*)(A + ga + (size_t)(i * 64) * KD + t * 64),
        (lv_t*)((char*)&As[0] + r3 * 32768 + i * 8192 + dw), 16, 0, 0);
  };
  auto stageB = [&](int t, int r3, int j) {
    __builtin_amdgcn_global_load_lds(
        (gv_t*)(Bt + gb + (size_t)(j * 64) * KD + t * 64),
        (lv_t*)((char*)&Bs[0] + r3 * 16384 + j * 8192 + dw), 16, 0, 0);
  };

  // ---- compute-side LDS offsets ----
  const int rl = lane & 15;            // fragment row/col within 16
  const int ql = lane >> 4;            // k sub-chunk 0..3
  const int wm = (w >> 1) * 64;        // wave M offset (4 positions)
  const int wn = (w & 1) * 64;         // wave N offset (2 positions)
  const int so0 = (ql ^ (rl & 7)) * 8; // ks=0 slot offset (ushorts); ks=1: ^32
  const int ra = (wm + rl) * 64;       // + mi*1024 per 16-row fragment
  const int rb = (wn + rl) * 64;       // + nj*1024

  floatx4 acc[4][4];
#pragma unroll
  for (int mi = 0; mi < 4; ++mi)
#pragma unroll
    for (int nj = 0; nj < 4; ++nj) acc[mi][nj] = (floatx4){0.f, 0.f, 0.f, 0.f};

  // ---- prologue: stage tiles 0,1; drain tile 0 (leave tile 1 in flight) --
#pragma unroll
  for (int i = 0; i < 4; ++i) stageA(0, 0, i);
#pragma unroll
  for (int j = 0; j < 2; ++j) stageB(0, 0, j);
#pragma unroll
  for (int i = 0; i < 4; ++i) stageA(1, 1, i);
#pragma unroll
  for (int j = 0; j < 2; ++j) stageB(1, 1, j);
  asm volatile("s_waitcnt vmcnt(6)\n\ts_barrier" ::: "memory");

  int rc = 0, rs = 2;  // ring slot of tile t / of tile t+2
  for (int t = 0; t < 12; ++t) {
    const ushort_t* Ab = &As[rc * 16384];
    const ushort_t* Bb = &Bs[rc * 8192];
    bf16x8 av[4], bv[4];

    // ===== phase 0 (ks = 0) =====
#pragma unroll
    for (int mi = 0; mi < 4; ++mi)
      av[mi] =
          __builtin_bit_cast(bf16x8, *(const ushort8*)&Ab[ra + mi * 1024 + so0]);
#pragma unroll
    for (int nj = 0; nj < 4; ++nj)
      bv[nj] =
          __builtin_bit_cast(bf16x8, *(const ushort8*)&Bb[rb + nj * 1024 + so0]);
    if (t < 10) {
      stageA(t + 2, rs, 0);
      stageA(t + 2, rs, 1);
      stageA(t + 2, rs, 2);
    }
    asm volatile("s_barrier" ::: "memory");
    __builtin_amdgcn_s_setprio(1);
#pragma unroll
    for (int mi = 0; mi < 4; ++mi)
#pragma unroll
      for (int nj = 0; nj < 4; ++nj)
        acc[mi][nj] = __builtin_amdgcn_mfma_f32_16x16x32_bf16(
            av[mi], bv[nj], acc[mi][nj], 0, 0, 0);
    __builtin_amdgcn_s_setprio(0);
    asm volatile("s_barrier" ::: "memory");

    // ===== phase 1 (ks = 1) =====
    const int so1 = so0 ^ 32;
#pragma unroll
    for (int mi = 0; mi < 4; ++mi)
      av[mi] =
          __builtin_bit_cast(bf16x8, *(const ushort8*)&Ab[ra + mi * 1024 + so1]);
#pragma unroll
    for (int nj = 0; nj < 4; ++nj)
      bv[nj] =
          __builtin_bit_cast(bf16x8, *(const ushort8*)&Bb[rb + nj * 1024 + so1]);
    if (t < 10) {
      stageA(t + 2, rs, 3);
      stageB(t + 2, rs, 0);
      stageB(t + 2, rs, 1);
    }
    // Inter-tile gate: drain tile t+1's 6 loads; tile t+2's 6 stay in flight.
    if (t < 10)
      asm volatile("s_waitcnt vmcnt(6)\n\ts_barrier" ::: "memory");
    else if (t == 10)
      asm volatile("s_waitcnt vmcnt(0)\n\ts_barrier" ::: "memory");
    else
      asm volatile("s_barrier" ::: "memory");
    __builtin_amdgcn_s_setprio(1);
#pragma unroll
    for (int mi = 0; mi < 4; ++mi)
#pragma unroll
      for (int nj = 0; nj < 4; ++nj)
        acc[mi][nj] = __builtin_amdgcn_mfma_f32_16x16x32_bf16(
            av[mi], bv[nj], acc[mi][nj], 0, 0, 0);
    __builtin_amdgcn_s_setprio(0);
    asm volatile("s_barrier" ::: "memory");

    rc = rc == 2 ? 0 : rc + 1;
    rs = rs == 2 ? 0 : rs + 1;
  }

  // ---- epilogue: D[row=(lane>>4)*4+p][col=lane&15] per 16x16 fragment ----
#pragma unroll
  for (int nj = 0; nj < 4; ++nj) {
    const int cc = n0 + wn + nj * 16 + rl;
    const float bvs = bias[cc];
#pragma unroll
    for (int mi = 0; mi < 4; ++mi) {
      const int rbase = m0 + wm + mi * 16 + ql * 4;
#pragma unroll
      for (int p = 0; p < 4; ++p) {
        float v = acc[mi][nj][p] + bvs;
        if (MODE == 1) {
          v = v > 0.f ? v : 0.f;
          ((__hip_bfloat16*)outp)[(size_t)(rbase + p) * KD + cc] =
              __float2bfloat16(v);
        } else {
          v += __bfloat162float(emb[(size_t)(rbase + p) * KD + cc]);
          ((float*)outp)[(size_t)(rbase + p) * KD + cc] = v;
        }
      }
    }
  }
}

// ---------------------------------------------------------------------------
extern "C" void kernel_launch(void* const* d_in, const int* in_sizes, int n_in,
                              void* d_out, int out_size, void* d_ws,
                              size_t ws_size, hipStream_t stream) {
  const float* x = (const float*)d_in[0];
  const float* cw = (const float*)d_in[1];
  const float* w1 = (const float*)d_in[2];
  const float* b1 = (const float*)d_in[3];
  const float* w2 = (const float*)d_in[4];
  const float* b2 = (const float*)d_in[5];
  // d_in[6] = reverse flag, unused by the reference computation.
  float* out = (float*)d_out;

  // Chunk the 1344 (b,c) series so emb/hidden bf16 intermediates fit d_ws
  // (and stay L3-resident). NC=4 -> ~134 MB of workspace; cn even so cn*128
  // is a multiple of 256 (GEMM BM).
  int NC = 4;
  while (NC < 32) {
    size_t cn_ = 1344 / NC;
    size_t need = 2 * (size_t)KD * KD * 2 + 2 * cn_ * 128 * KD * 2;
    if (need <= ws_size) break;
    NC *= 2;
  }
  const int cn = 1344 / NC;
  const int mt = cn / 2;  // 256-row M tiles per chunk

  __hip_bfloat16* w1t = (__hip_bfloat16*)d_ws;
  __hip_bfloat16* w2t = w1t + (size_t)KD * KD;
  __hip_bfloat16* embc = w2t + (size_t)KD * KD;
  __hip_bfloat16* hidc = embc + (size_t)cn * 128 * KD;

  transpose_cvt_kernel<<<576, 256, 0, stream>>>(w1, w1t);
  transpose_cvt_kernel<<<576, 256, 0, stream>>>(w2, w2t);

  for (int c = 0; c < NC; ++c) {
    const int nb = c * cn;
    conv_kernel<<<dim3(cn, 3), 256, 0, stream>>>(x, cw, embc, nb);
    gemm_kernel<1><<<dim3(mt * 6), 512, 0, stream>>>(embc, w1t, b1, nullptr,
                                                     (void*)hidc, mt);
    gemm_kernel<2><<<dim3(mt * 6), 512, 0, stream>>>(
        hidc, w2t, b2, embc, (void*)(out + (size_t)nb * 128 * KD), mt);
  }
}

// Round 4
// 1170.264 us; speedup vs baseline: 1.2197x; 1.0720x over previous
//
#include <hip/hip_runtime.h>
#include <hip/hip_bf16.h>

typedef __bf16 bf16x8 __attribute__((ext_vector_type(8)));
typedef float floatx4 __attribute__((ext_vector_type(4)));
typedef unsigned short ushort_t;
typedef ushort_t ushort8 __attribute__((ext_vector_type(8)));

#define KD 768   // d_model

// ---------------------------------------------------------------------------
// transpose + convert: dst[n][k] = bf16(src[k][n]), 768x768  (used for W2)
// ---------------------------------------------------------------------------
__global__ __launch_bounds__(256) void transpose_cvt_kernel(
    const float* __restrict__ src, __hip_bfloat16* __restrict__ dst) {
  __shared__ float tile[32][33];
  const int bx = blockIdx.x % 24;  // src col tile
  const int by = blockIdx.x / 24;  // src row tile
  const int tx = threadIdx.x & 31;
  const int ty = threadIdx.x >> 5;
#pragma unroll
  for (int i = 0; i < 32; i += 8)
    tile[ty + i][tx] = src[(size_t)(by * 32 + ty + i) * KD + bx * 32 + tx];
  __syncthreads();
#pragma unroll
  for (int i = 0; i < 32; i += 8)
    dst[(size_t)(bx * 32 + ty + i) * KD + by * 32 + tx] =
        __float2bfloat16(tile[tx][ty + i]);
}

// ---------------------------------------------------------------------------
// W1cT[n][e] = sum_o Wc'[e][o] * W1[o][n],  e = kk*16+i (i<16 patch elem,
// kk<3 tap), Wc'[e][o] = cw[o*48 + i*3 + kk].  f32 accumulate, bf16 store.
// Pad columns e=48..63 zeroed. Grid (48,3), 256 threads.
// ---------------------------------------------------------------------------
__global__ __launch_bounds__(256) void w1c_kernel(
    const float* __restrict__ cw, const float* __restrict__ w1,
    __hip_bfloat16* __restrict__ w1ct) {
  __shared__ float wcrow[768];
  const int e = blockIdx.x;  // 0..47
  const int nb = blockIdx.y * 256 + threadIdx.x;
  const int i = e & 15, kk = e >> 4;
  for (int o = threadIdx.x; o < 768; o += 256)
    wcrow[o] = cw[(size_t)o * 48 + i * 3 + kk];
  __syncthreads();
  float acc = 0.f;
  for (int o = 0; o < 768; ++o)
    acc = fmaf(wcrow[o], w1[(size_t)o * KD + nb], acc);
  w1ct[(size_t)nb * 64 + e] = __float2bfloat16(acc);
  if (e == 0) {
#pragma unroll
    for (int ez = 48; ez < 64; ++ez)
      w1ct[(size_t)nb * 64 + ez] = __float2bfloat16(0.f);
  }
}

// ---------------------------------------------------------------------------
// patchify: P[(n*128+p)][e] = bf16(win(p + (e>>4) - 1)[e&15]), e<48; 0 else.
// win(q)[i] = xs[q*8+i] with xs = x row edge-padded to 1032 (xs[1024..1031]
// = x[1023]); window index circular mod 128 (win(-1) = win(127) incl. edge
// semantics -> matches the reference's circular concat of edge-padded
// patches). One block per series, 128 threads (thread = patch).
// ---------------------------------------------------------------------------
__global__ __launch_bounds__(128) void patchify_kernel(
    const float* __restrict__ x, __hip_bfloat16* __restrict__ P) {
  __shared__ float xs[1032];
  const int n = blockIdx.x;
  const int tid = threadIdx.x;
  const float* xr = x + (size_t)n * 1024;
  const float4* xr4 = (const float4*)xr;
  float4* xs4 = (float4*)xs;
  for (int j = tid; j < 256; j += 128) xs4[j] = xr4[j];
  if (tid < 8) xs[1024 + tid] = xr[1023];
  __syncthreads();
  const int p = tid;
  __hip_bfloat16 row[64];
#pragma unroll
  for (int kk = 0; kk < 3; ++kk) {
    const int q = (p + kk + 127) & 127;
#pragma unroll
    for (int i = 0; i < 16; ++i)
      row[kk * 16 + i] = __float2bfloat16(xs[q * 8 + i]);
  }
#pragma unroll
  for (int i = 48; i < 64; ++i) row[i] = __float2bfloat16(0.f);
  __hip_bfloat16* pr = P + ((size_t)n * 128 + p) * 64;
#pragma unroll
  for (int s = 0; s < 8; ++s)
    *(ushort8*)&pr[s * 8] = *(const ushort8*)&row[s * 8];
}

// ---------------------------------------------------------------------------
// Conv / patch embedding (f32, unchanged; produces the residual emb).
// ---------------------------------------------------------------------------
__device__ __forceinline__ void load_patch(const float* __restrict__ xr,
                                           int qw, float* b) {
  if (qw < 127) {
    const float4* p4 = (const float4*)(xr + qw * 8);
    float4 v0 = p4[0], v1 = p4[1], v2 = p4[2], v3 = p4[3];
    b[0] = v0.x; b[1] = v0.y; b[2] = v0.z; b[3] = v0.w;
    b[4] = v1.x; b[5] = v1.y; b[6] = v1.z; b[7] = v1.w;
    b[8] = v2.x; b[9] = v2.y; b[10] = v2.z; b[11] = v2.w;
    b[12] = v3.x; b[13] = v3.y; b[14] = v3.z; b[15] = v3.w;
  } else {
    float4 v0 = *(const float4*)(xr + 1016);
    float4 v1 = *(const float4*)(xr + 1020);
    b[0] = v0.x; b[1] = v0.y; b[2] = v0.z; b[3] = v0.w;
    b[4] = v1.x; b[5] = v1.y; b[6] = v1.z; b[7] = v1.w;
    float e = v1.w;  // x[1023], edge value
#pragma unroll
    for (int i = 8; i < 16; ++i) b[i] = e;
  }
}

__global__ __launch_bounds__(256) void conv_kernel(
    const float* __restrict__ x, const float* __restrict__ cw,
    __hip_bfloat16* __restrict__ emb, int nb) {
  const int lb = blockIdx.x;
  const int n = nb + lb;
  const float* xr = x + (size_t)n * 1024;
  const int o = blockIdx.y * 256 + threadIdx.x;

  float w[48];
  const float4* wp = (const float4*)(cw + (size_t)o * 48);
#pragma unroll
  for (int q = 0; q < 12; ++q) {
    float4 v = wp[q];
    w[q * 4 + 0] = v.x; w[q * 4 + 1] = v.y;
    w[q * 4 + 2] = v.z; w[q * 4 + 3] = v.w;
  }

  __hip_bfloat16* erow = emb + (size_t)lb * 128 * KD + o;
  float P0[16], P1[16], P2[16], P3[16];

  auto pair = [&](const float* Pa, const float* Pb, const float* Pc,
                  const float* Pd, int p) {
    float a0 = 0.f, a1 = 0.f;
#pragma unroll
    for (int i = 0; i < 16; ++i) {
      a0 += w[i * 3 + 0] * Pa[i];
      a0 += w[i * 3 + 1] * Pb[i];
      a0 += w[i * 3 + 2] * Pc[i];
      a1 += w[i * 3 + 0] * Pb[i];
      a1 += w[i * 3 + 1] * Pc[i];
      a1 += w[i * 3 + 2] * Pd[i];
    }
    erow[(size_t)p * KD] = __float2bfloat16(a0);
    erow[(size_t)(p + 1) * KD] = __float2bfloat16(a1);
  };

  load_patch(xr, 127, P0);
  load_patch(xr, 0, P1);
  for (int p = 0; p < 128; p += 4) {
    load_patch(xr, p + 1, P2);
    load_patch(xr, (p + 2) & 127, P3);
    pair(P0, P1, P2, P3, p);
    load_patch(xr, (p + 3) & 127, P0);
    load_patch(xr, (p + 4) & 127, P1);
    pair(P2, P3, P0, P1, p + 2);
  }
}

// ---------------------------------------------------------------------------
// pgemm: hid = relu(P @ W1c + b1).  M x 64(K) x 768(N).  Single-shot MFMA:
// BM=BN=256, 8 waves (2M x 4N), wave owns 128x64.  LDS 2x32 KiB, round-3-
// proven swizzle (slot = chunk ^ (row&7), inverse-permuted global source).
// Output-write-bound (~66 MB bf16 per chunk); no pipelining needed.
// ---------------------------------------------------------------------------
__global__ __launch_bounds__(512, 2) void pgemm_kernel(
    const __hip_bfloat16* __restrict__ P, const __hip_bfloat16* __restrict__ Bt,
    const float* __restrict__ bias, __hip_bfloat16* __restrict__ out) {
  __shared__ __align__(16) ushort_t As[256 * 64];
  __shared__ __align__(16) ushort_t Bs[256 * 64];
  const int tid = threadIdx.x;
  const int lane = tid & 63;
  const int w = __builtin_amdgcn_readfirstlane(tid >> 6);
  const int m0 = blockIdx.x * 256;
  const int n0 = blockIdx.y * 256;

  const int srow = tid >> 3;                  // 0..63 within a 64-row slab
  const int schunk = (tid & 7) ^ (srow & 7);  // inverse-swizzled source chunk
  const size_t ga = (size_t)(m0 + srow) * 64 + schunk * 8;
  const size_t gb = (size_t)(n0 + srow) * 64 + schunk * 8;
  typedef __attribute__((address_space(3))) void lv_t;
  typedef __attribute__((address_space(1))) const void gv_t;
  const int dw = w * 1024;
#pragma unroll
  for (int i = 0; i < 4; ++i)
    __builtin_amdgcn_global_load_lds(
        (gv_t*)(P + ga + (size_t)(i * 64) * 64),
        (lv_t*)((char*)&As[0] + i * 8192 + dw), 16, 0, 0);
#pragma unroll
  for (int i = 0; i < 4; ++i)
    __builtin_amdgcn_global_load_lds(
        (gv_t*)(Bt + gb + (size_t)(i * 64) * 64),
        (lv_t*)((char*)&Bs[0] + i * 8192 + dw), 16, 0, 0);
  asm volatile("s_waitcnt vmcnt(0)\n\ts_barrier" ::: "memory");

  const int rl = lane & 15;
  const int ql = lane >> 4;
  const int wm = (w >> 2) * 128;  // 2 M-positions
  const int wn = (w & 3) * 64;    // 4 N-positions
  const int so0 = (ql ^ (rl & 7)) * 8;
  const int ra = (wm + rl) * 64;
  const int rb = (wn + rl) * 64;

  floatx4 acc[8][4];
#pragma unroll
  for (int mi = 0; mi < 8; ++mi)
#pragma unroll
    for (int nj = 0; nj < 4; ++nj) acc[mi][nj] = (floatx4){0.f, 0.f, 0.f, 0.f};

#pragma unroll
  for (int ks = 0; ks < 2; ++ks) {
    const int so = so0 ^ (ks * 32);
    bf16x8 av[8], bv[4];
#pragma unroll
    for (int mi = 0; mi < 8; ++mi)
      av[mi] =
          __builtin_bit_cast(bf16x8, *(const ushort8*)&As[ra + mi * 1024 + so]);
#pragma unroll
    for (int nj = 0; nj < 4; ++nj)
      bv[nj] =
          __builtin_bit_cast(bf16x8, *(const ushort8*)&Bs[rb + nj * 1024 + so]);
#pragma unroll
    for (int mi = 0; mi < 8; ++mi)
#pragma unroll
      for (int nj = 0; nj < 4; ++nj)
        acc[mi][nj] = __builtin_amdgcn_mfma_f32_16x16x32_bf16(
            av[mi], bv[nj], acc[mi][nj], 0, 0, 0);
  }

#pragma unroll
  for (int nj = 0; nj < 4; ++nj) {
    const int cc = n0 + wn + nj * 16 + rl;
    const float bvs = bias[cc];
#pragma unroll
    for (int mi = 0; mi < 8; ++mi) {
      const int rbase = m0 + wm + mi * 16 + ql * 4;
#pragma unroll
      for (int p = 0; p < 4; ++p) {
        float v = acc[mi][nj][p] + bvs;
        v = v > 0.f ? v : 0.f;
        out[(size_t)(rbase + p) * KD + cc] = __float2bfloat16(v);
      }
    }
  }
}

// ---------------------------------------------------------------------------
// GEMM2 (round-3 kernel, MODE 2 only): out = float(emb) + hid@W2 + b2.
// BM=256 / BN=128 / BK=64, 8 waves (4M x 2N), ring-3 LDS, phase-split
// schedule with counted vmcnt(6) (verified round 3).
// ---------------------------------------------------------------------------
template <int MODE>
__global__ __launch_bounds__(512, 2) void gemm_kernel(
    const __hip_bfloat16* __restrict__ A, const __hip_bfloat16* __restrict__ Bt,
    const float* __restrict__ bias, const __hip_bfloat16* __restrict__ emb,
    void* __restrict__ outp, int mt) {
  __shared__ __align__(16) ushort_t As[3 * 256 * 64];  // 96 KiB ring-3
  __shared__ __align__(16) ushort_t Bs[3 * 128 * 64];  // 48 KiB ring-3
  const int tid = threadIdx.x;
  const int lane = tid & 63;
  const int w = __builtin_amdgcn_readfirstlane(tid >> 6);

  const int total = mt * 6;
  const int q8 = total >> 3, r8 = total & 7;
  const int xcd = blockIdx.x & 7;
  const int j8 = blockIdx.x >> 3;
  const int wg =
      (xcd < r8 ? xcd * (q8 + 1) : r8 * (q8 + 1) + (xcd - r8) * q8) + j8;
  const int m0 = (wg / 6) * 256;
  const int n0 = (wg % 6) * 128;

  const int srow = tid >> 3;
  const int schunk = (tid & 7) ^ (srow & 7);
  const size_t ga = (size_t)(m0 + srow) * KD + schunk * 8;
  const size_t gb = (size_t)(n0 + srow) * KD + schunk * 8;
  typedef __attribute__((address_space(3))) void lv_t;
  typedef __attribute__((address_space(1))) const void gv_t;
  const int dw = w * 1024;

  auto stageA = [&](int t, int r3, int i) {
    __builtin_amdgcn_global_load_lds(
        (gv_t*)(A + ga + (size_t)(i * 64) * KD + t * 64),
        (lv_t*)((char*)&As[0] + r3 * 32768 + i * 8192 + dw), 16, 0, 0);
  };
  auto stageB = [&](int t, int r3, int j) {
    __builtin_amdgcn_global_load_lds(
        (gv_t*)(Bt + gb + (size_t)(j * 64) * KD + t * 64),
        (lv_t*)((char*)&Bs[0] + r3 * 16384 + j * 8192 + dw), 16, 0, 0);
  };

  const int rl = lane & 15;
  const int ql = lane >> 4;
  const int wm = (w >> 1) * 64;
  const int wn = (w & 1) * 64;
  const int so0 = (ql ^ (rl & 7)) * 8;
  const int ra = (wm + rl) * 64;
  const int rb = (wn + rl) * 64;

  floatx4 acc[4][4];
#pragma unroll
  for (int mi = 0; mi < 4; ++mi)
#pragma unroll
    for (int nj = 0; nj < 4; ++nj) acc[mi][nj] = (floatx4){0.f, 0.f, 0.f, 0.f};

#pragma unroll
  for (int i = 0; i < 4; ++i) stageA(0, 0, i);
#pragma unroll
  for (int j = 0; j < 2; ++j) stageB(0, 0, j);
#pragma unroll
  for (int i = 0; i < 4; ++i) stageA(1, 1, i);
#pragma unroll
  for (int j = 0; j < 2; ++j) stageB(1, 1, j);
  asm volatile("s_waitcnt vmcnt(6)\n\ts_barrier" ::: "memory");

  int rc = 0, rs = 2;
  for (int t = 0; t < 12; ++t) {
    const ushort_t* Ab = &As[rc * 16384];
    const ushort_t* Bb = &Bs[rc * 8192];
    bf16x8 av[4], bv[4];

    // ===== phase 0 (ks = 0) =====
#pragma unroll
    for (int mi = 0; mi < 4; ++mi)
      av[mi] =
          __builtin_bit_cast(bf16x8, *(const ushort8*)&Ab[ra + mi * 1024 + so0]);
#pragma unroll
    for (int nj = 0; nj < 4; ++nj)
      bv[nj] =
          __builtin_bit_cast(bf16x8, *(const ushort8*)&Bb[rb + nj * 1024 + so0]);
    if (t < 10) {
      stageA(t + 2, rs, 0);
      stageA(t + 2, rs, 1);
      stageA(t + 2, rs, 2);
    }
    asm volatile("s_barrier" ::: "memory");
    __builtin_amdgcn_s_setprio(1);
#pragma unroll
    for (int mi = 0; mi < 4; ++mi)
#pragma unroll
      for (int nj = 0; nj < 4; ++nj)
        acc[mi][nj] = __builtin_amdgcn_mfma_f32_16x16x32_bf16(
            av[mi], bv[nj], acc[mi][nj], 0, 0, 0);
    __builtin_amdgcn_s_setprio(0);
    asm volatile("s_barrier" ::: "memory");

    // ===== phase 1 (ks = 1) =====
    const int so1 = so0 ^ 32;
#pragma unroll
    for (int mi = 0; mi < 4; ++mi)
      av[mi] =
          __builtin_bit_cast(bf16x8, *(const ushort8*)&Ab[ra + mi * 1024 + so1]);
#pragma unroll
    for (int nj = 0; nj < 4; ++nj)
      bv[nj] =
          __builtin_bit_cast(bf16x8, *(const ushort8*)&Bb[rb + nj * 1024 + so1]);
    if (t < 10) {
      stageA(t + 2, rs, 3);
      stageB(t + 2, rs, 0);
      stageB(t + 2, rs, 1);
    }
    if (t < 10)
      asm volatile("s_waitcnt vmcnt(6)\n\ts_barrier" ::: "memory");
    else if (t == 10)
      asm volatile("s_waitcnt vmcnt(0)\n\ts_barrier" ::: "memory");
    else
      asm volatile("s_barrier" ::: "memory");
    __builtin_amdgcn_s_setprio(1);
#pragma unroll
    for (int mi = 0; mi < 4; ++mi)
#pragma unroll
      for (int nj = 0; nj < 4; ++nj)
        acc[mi][nj] = __builtin_amdgcn_mfma_f32_16x16x32_bf16(
            av[mi], bv[nj], acc[mi][nj], 0, 0, 0);
    __builtin_amdgcn_s_setprio(0);
    asm volatile("s_barrier" ::: "memory");

    rc = rc == 2 ? 0 : rc + 1;
    rs = rs == 2 ? 0 : rs + 1;
  }

#pragma unroll
  for (int nj = 0; nj < 4; ++nj) {
    const int cc = n0 + wn + nj * 16 + rl;
    const float bvs = bias[cc];
#pragma unroll
    for (int mi = 0; mi < 4; ++mi) {
      const int rbase = m0 + wm + mi * 16 + ql * 4;
#pragma unroll
      for (int p = 0; p < 4; ++p) {
        float v = acc[mi][nj][p] + bvs;
        if (MODE == 1) {
          v = v > 0.f ? v : 0.f;
          ((__hip_bfloat16*)outp)[(size_t)(rbase + p) * KD + cc] =
              __float2bfloat16(v);
        } else {
          v += __bfloat162float(emb[(size_t)(rbase + p) * KD + cc]);
          ((float*)outp)[(size_t)(rbase + p) * KD + cc] = v;
        }
      }
    }
  }
}

// ---------------------------------------------------------------------------
extern "C" void kernel_launch(void* const* d_in, const int* in_sizes, int n_in,
                              void* d_out, int out_size, void* d_ws,
                              size_t ws_size, hipStream_t stream) {
  const float* x = (const float*)d_in[0];
  const float* cw = (const float*)d_in[1];
  const float* w1 = (const float*)d_in[2];
  const float* b1 = (const float*)d_in[3];
  const float* w2 = (const float*)d_in[4];
  const float* b2 = (const float*)d_in[5];
  float* out = (float*)d_out;

  const size_t M_ALL = 1344 * 128;
  // fixed workspace: w2t (768x768 bf16), w1ct (768x64 bf16), P (M_ALL x 64)
  const size_t fixed = (size_t)KD * KD * 2 + (size_t)KD * 64 * 2 + M_ALL * 64 * 2;
  int NC = 4;
  while (NC < 32) {
    size_t cn_ = 1344 / NC;
    size_t need = fixed + 2 * cn_ * 128 * KD * 2;
    if (need <= ws_size) break;
    NC *= 2;
  }
  const int cn = 1344 / NC;
  const int mt = cn / 2;  // 256-row M tiles per chunk

  __hip_bfloat16* w2t = (__hip_bfloat16*)d_ws;
  __hip_bfloat16* w1ct = w2t + (size_t)KD * KD;
  __hip_bfloat16* Pm = w1ct + (size_t)KD * 64;
  __hip_bfloat16* embc = Pm + M_ALL * 64;
  __hip_bfloat16* hidc = embc + (size_t)cn * 128 * KD;

  transpose_cvt_kernel<<<576, 256, 0, stream>>>(w2, w2t);
  w1c_kernel<<<dim3(48, 3), 256, 0, stream>>>(cw, w1, w1ct);
  patchify_kernel<<<1344, 128, 0, stream>>>(x, Pm);

  for (int c = 0; c < NC; ++c) {
    const int nb = c * cn;
    conv_kernel<<<dim3(cn, 3), 256, 0, stream>>>(x, cw, embc, nb);
    pgemm_kernel<<<dim3(mt, 3), 512, 0, stream>>>(
        Pm + (size_t)nb * 128 * 64, w1ct, b1, hidc);
    gemm_kernel<2><<<dim3(mt * 6), 512, 0, stream>>>(
        hidc, w2t, b2, embc, (void*)(out + (size_t)nb * 128 * KD), mt);
  }
}

// Round 5
// 965.572 us; speedup vs baseline: 1.4783x; 1.2120x over previous
//
#include <hip/hip_runtime.h>
#include <hip/hip_bf16.h>

typedef __bf16 bf16x8 __attribute__((ext_vector_type(8)));
typedef float floatx4 __attribute__((ext_vector_type(4)));
typedef unsigned short ushort_t;
typedef ushort_t ushort8 __attribute__((ext_vector_type(8)));

#define KD 768   // d_model

// ---------------------------------------------------------------------------
// transpose + convert: dst[n][k] = bf16(src[k][n]), 768x768  (used for W2)
// ---------------------------------------------------------------------------
__global__ __launch_bounds__(256) void transpose_cvt_kernel(
    const float* __restrict__ src, __hip_bfloat16* __restrict__ dst) {
  __shared__ float tile[32][33];
  const int bx = blockIdx.x % 24;  // src col tile
  const int by = blockIdx.x / 24;  // src row tile
  const int tx = threadIdx.x & 31;
  const int ty = threadIdx.x >> 5;
#pragma unroll
  for (int i = 0; i < 32; i += 8)
    tile[ty + i][tx] = src[(size_t)(by * 32 + ty + i) * KD + bx * 32 + tx];
  __syncthreads();
#pragma unroll
  for (int i = 0; i < 32; i += 8)
    dst[(size_t)(bx * 32 + ty + i) * KD + by * 32 + tx] =
        __float2bfloat16(tile[tx][ty + i]);
}

// ---------------------------------------------------------------------------
// W1cT[n][e] = sum_o Wc'[e][o] * W1[o][n],  e = kk*16+i (i<16 patch elem,
// kk<3 tap), Wc'[e][o] = cw[o*48 + i*3 + kk].  f32 accumulate, bf16 store.
// Pad columns e=48..63 zeroed. Grid (48,3), 256 threads.
// ---------------------------------------------------------------------------
__global__ __launch_bounds__(256) void w1c_kernel(
    const float* __restrict__ cw, const float* __restrict__ w1,
    __hip_bfloat16* __restrict__ w1ct) {
  __shared__ float wcrow[768];
  const int e = blockIdx.x;  // 0..47
  const int nb = blockIdx.y * 256 + threadIdx.x;
  const int i = e & 15, kk = e >> 4;
  for (int o = threadIdx.x; o < 768; o += 256)
    wcrow[o] = cw[(size_t)o * 48 + i * 3 + kk];
  __syncthreads();
  float acc = 0.f;
  for (int o = 0; o < 768; ++o)
    acc = fmaf(wcrow[o], w1[(size_t)o * KD + nb], acc);
  w1ct[(size_t)nb * 64 + e] = __float2bfloat16(acc);
  if (e == 0) {
#pragma unroll
    for (int ez = 48; ez < 64; ++ez)
      w1ct[(size_t)nb * 64 + ez] = __float2bfloat16(0.f);
  }
}

// ---------------------------------------------------------------------------
// WcE[o][e] = bf16(cw[o*48 + (e&15)*3 + (e>>4)]) for e<48, else 0.
// B^T-layout conv weights for the fused emb tile in gemm2f. Grid 768, 64 thr.
// ---------------------------------------------------------------------------
__global__ __launch_bounds__(64) void wce_kernel(
    const float* __restrict__ cw, __hip_bfloat16* __restrict__ wce) {
  const int o = blockIdx.x;
  const int e = threadIdx.x;
  float v = 0.f;
  if (e < 48) v = cw[(size_t)o * 48 + (e & 15) * 3 + (e >> 4)];
  wce[(size_t)o * 64 + e] = __float2bfloat16(v);
}

// ---------------------------------------------------------------------------
// patchify: P[(n*128+p)][e] = bf16(win(p + (e>>4) - 1)[e&15]), e<48; 0 else.
// win(q)[i] = xs[q*8+i], xs = x row edge-padded to 1032; window circular
// mod 128 (matches reference semantics). One block per series, 128 threads.
// ---------------------------------------------------------------------------
__global__ __launch_bounds__(128) void patchify_kernel(
    const float* __restrict__ x, __hip_bfloat16* __restrict__ P) {
  __shared__ float xs[1032];
  const int n = blockIdx.x;
  const int tid = threadIdx.x;
  const float* xr = x + (size_t)n * 1024;
  const float4* xr4 = (const float4*)xr;
  float4* xs4 = (float4*)xs;
  for (int j = tid; j < 256; j += 128) xs4[j] = xr4[j];
  if (tid < 8) xs[1024 + tid] = xr[1023];
  __syncthreads();
  const int p = tid;
  __hip_bfloat16 row[64];
#pragma unroll
  for (int kk = 0; kk < 3; ++kk) {
    const int q = (p + kk + 127) & 127;
#pragma unroll
    for (int i = 0; i < 16; ++i)
      row[kk * 16 + i] = __float2bfloat16(xs[q * 8 + i]);
  }
#pragma unroll
  for (int i = 48; i < 64; ++i) row[i] = __float2bfloat16(0.f);
  __hip_bfloat16* pr = P + ((size_t)n * 128 + p) * 64;
#pragma unroll
  for (int s = 0; s < 8; ++s)
    *(ushort8*)&pr[s * 8] = *(const ushort8*)&row[s * 8];
}

// ---------------------------------------------------------------------------
// pgemm: hid = relu(P @ W1c + b1).  M x 64(K) x 768(N).  Single-shot MFMA:
// BM=BN=256, 8 waves (2M x 4N), wave owns 128x64.  Proven swizzle
// (slot = chunk ^ (row&7), inverse-permuted global source). Write-bound.
// ---------------------------------------------------------------------------
__global__ __launch_bounds__(512, 2) void pgemm_kernel(
    const __hip_bfloat16* __restrict__ P, const __hip_bfloat16* __restrict__ Bt,
    const float* __restrict__ bias, __hip_bfloat16* __restrict__ out) {
  __shared__ __align__(16) ushort_t As[256 * 64];
  __shared__ __align__(16) ushort_t Bs[256 * 64];
  const int tid = threadIdx.x;
  const int lane = tid & 63;
  const int w = __builtin_amdgcn_readfirstlane(tid >> 6);
  const int m0 = blockIdx.x * 256;
  const int n0 = blockIdx.y * 256;

  const int srow = tid >> 3;                  // 0..63 within a 64-row slab
  const int schunk = (tid & 7) ^ (srow & 7);  // inverse-swizzled source chunk
  const size_t ga = (size_t)(m0 + srow) * 64 + schunk * 8;
  const size_t gb = (size_t)(n0 + srow) * 64 + schunk * 8;
  typedef __attribute__((address_space(3))) void lv_t;
  typedef __attribute__((address_space(1))) const void gv_t;
  const int dw = w * 1024;
#pragma unroll
  for (int i = 0; i < 4; ++i)
    __builtin_amdgcn_global_load_lds(
        (gv_t*)(P + ga + (size_t)(i * 64) * 64),
        (lv_t*)((char*)&As[0] + i * 8192 + dw), 16, 0, 0);
#pragma unroll
  for (int i = 0; i < 4; ++i)
    __builtin_amdgcn_global_load_lds(
        (gv_t*)(Bt + gb + (size_t)(i * 64) * 64),
        (lv_t*)((char*)&Bs[0] + i * 8192 + dw), 16, 0, 0);
  asm volatile("s_waitcnt vmcnt(0)\n\ts_barrier" ::: "memory");

  const int rl = lane & 15;
  const int ql = lane >> 4;
  const int wm = (w >> 2) * 128;  // 2 M-positions
  const int wn = (w & 3) * 64;    // 4 N-positions
  const int so0 = (ql ^ (rl & 7)) * 8;
  const int ra = (wm + rl) * 64;
  const int rb = (wn + rl) * 64;

  floatx4 acc[8][4];
#pragma unroll
  for (int mi = 0; mi < 8; ++mi)
#pragma unroll
    for (int nj = 0; nj < 4; ++nj) acc[mi][nj] = (floatx4){0.f, 0.f, 0.f, 0.f};

#pragma unroll
  for (int ks = 0; ks < 2; ++ks) {
    const int so = so0 ^ (ks * 32);
    bf16x8 av[8], bv[4];
#pragma unroll
    for (int mi = 0; mi < 8; ++mi)
      av[mi] =
          __builtin_bit_cast(bf16x8, *(const ushort8*)&As[ra + mi * 1024 + so]);
#pragma unroll
    for (int nj = 0; nj < 4; ++nj)
      bv[nj] =
          __builtin_bit_cast(bf16x8, *(const ushort8*)&Bs[rb + nj * 1024 + so]);
#pragma unroll
    for (int mi = 0; mi < 8; ++mi)
#pragma unroll
      for (int nj = 0; nj < 4; ++nj)
        acc[mi][nj] = __builtin_amdgcn_mfma_f32_16x16x32_bf16(
            av[mi], bv[nj], acc[mi][nj], 0, 0, 0);
  }

#pragma unroll
  for (int nj = 0; nj < 4; ++nj) {
    const int cc = n0 + wn + nj * 16 + rl;
    const float bvs = bias[cc];
#pragma unroll
    for (int mi = 0; mi < 8; ++mi) {
      const int rbase = m0 + wm + mi * 16 + ql * 4;
#pragma unroll
      for (int p = 0; p < 4; ++p) {
        float v = acc[mi][nj][p] + bvs;
        v = v > 0.f ? v : 0.f;
        out[(size_t)(rbase + p) * KD + cc] = __float2bfloat16(v);
      }
    }
  }
}

// ---------------------------------------------------------------------------
// gemm2f: out = P@WcE^T (emb, fused as 13th K-tile) + hid@W2 + b2.   f32 out.
// BM=256 / BN=128 / BK=64, 8 waves (4M x 2N), ring-3 LDS, phase-split
// schedule with counted vmcnt(6) (structure verified rounds 3-4).
// Tile 12 = emb tile: A-source P (row stride 64), B-source WcE (row stride
// 64); cols 48..63 of both are zero so the pad contributes nothing.
// Ring ledger: tile 12 staged at t=10 into slot 0, consumed at t=12 (slot
// rc(12)=0); gates t<11 -> vmcnt(6), t==11 -> vmcnt(0), t==12 -> barrier.
// ---------------------------------------------------------------------------
__global__ __launch_bounds__(512, 2) void gemm2f_kernel(
    const __hip_bfloat16* __restrict__ A,    // hid, chunk-local M x 768
    const __hip_bfloat16* __restrict__ Bt,   // w2t, 768 x 768
    const __hip_bfloat16* __restrict__ P,    // chunk-local M x 64
    const __hip_bfloat16* __restrict__ WcE,  // 768 x 64
    const float* __restrict__ bias, float* __restrict__ out, int mt) {
  __shared__ __align__(16) ushort_t As[3 * 256 * 64];  // 96 KiB ring-3
  __shared__ __align__(16) ushort_t Bs[3 * 128 * 64];  // 48 KiB ring-3
  const int tid = threadIdx.x;
  const int lane = tid & 63;
  const int w = __builtin_amdgcn_readfirstlane(tid >> 6);

  // XCD-chunked bijective remap, n fastest within a chunk
  const int total = mt * 6;
  const int q8 = total >> 3, r8 = total & 7;
  const int xcd = blockIdx.x & 7;
  const int j8 = blockIdx.x >> 3;
  const int wg =
      (xcd < r8 ? xcd * (q8 + 1) : r8 * (q8 + 1) + (xcd - r8) * q8) + j8;
  const int m0 = (wg / 6) * 256;
  const int n0 = (wg % 6) * 128;

  const int srow = tid >> 3;
  const int schunk = (tid & 7) ^ (srow & 7);
  const size_t ga = (size_t)(m0 + srow) * KD + schunk * 8;
  const size_t gb = (size_t)(n0 + srow) * KD + schunk * 8;
  const size_t gap = (size_t)(m0 + srow) * 64 + schunk * 8;  // P side
  const size_t gbp = (size_t)(n0 + srow) * 64 + schunk * 8;  // WcE side
  typedef __attribute__((address_space(3))) void lv_t;
  typedef __attribute__((address_space(1))) const void gv_t;
  const int dw = w * 1024;

  auto stageA = [&](int t, int r3, int i) {
    const __hip_bfloat16* s =
        (t == 12) ? (P + gap + (size_t)(i * 64) * 64)
                  : (A + ga + (size_t)(i * 64) * KD + (size_t)t * 64);
    __builtin_amdgcn_global_load_lds(
        (gv_t*)s, (lv_t*)((char*)&As[0] + r3 * 32768 + i * 8192 + dw), 16, 0,
        0);
  };
  auto stageB = [&](int t, int r3, int j) {
    const __hip_bfloat16* s =
        (t == 12) ? (WcE + gbp + (size_t)(j * 64) * 64)
                  : (Bt + gb + (size_t)(j * 64) * KD + (size_t)t * 64);
    __builtin_amdgcn_global_load_lds(
        (gv_t*)s, (lv_t*)((char*)&Bs[0] + r3 * 16384 + j * 8192 + dw), 16, 0,
        0);
  };

  const int rl = lane & 15;
  const int ql = lane >> 4;
  const int wm = (w >> 1) * 64;  // 4 M-positions
  const int wn = (w & 1) * 64;   // 2 N-positions
  const int so0 = (ql ^ (rl & 7)) * 8;
  const int ra = (wm + rl) * 64;
  const int rb = (wn + rl) * 64;

  floatx4 acc[4][4];
#pragma unroll
  for (int mi = 0; mi < 4; ++mi)
#pragma unroll
    for (int nj = 0; nj < 4; ++nj) acc[mi][nj] = (floatx4){0.f, 0.f, 0.f, 0.f};

#pragma unroll
  for (int i = 0; i < 4; ++i) stageA(0, 0, i);
#pragma unroll
  for (int j = 0; j < 2; ++j) stageB(0, 0, j);
#pragma unroll
  for (int i = 0; i < 4; ++i) stageA(1, 1, i);
#pragma unroll
  for (int j = 0; j < 2; ++j) stageB(1, 1, j);
  asm volatile("s_waitcnt vmcnt(6)\n\ts_barrier" ::: "memory");

  int rc = 0, rs = 2;
  for (int t = 0; t < 13; ++t) {
    const ushort_t* Ab = &As[rc * 16384];
    const ushort_t* Bb = &Bs[rc * 8192];
    bf16x8 av[4], bv[4];

    // ===== phase 0 (ks = 0) =====
#pragma unroll
    for (int mi = 0; mi < 4; ++mi)
      av[mi] =
          __builtin_bit_cast(bf16x8, *(const ushort8*)&Ab[ra + mi * 1024 + so0]);
#pragma unroll
    for (int nj = 0; nj < 4; ++nj)
      bv[nj] =
          __builtin_bit_cast(bf16x8, *(const ushort8*)&Bb[rb + nj * 1024 + so0]);
    if (t < 11) {
      stageA(t + 2, rs, 0);
      stageA(t + 2, rs, 1);
      stageA(t + 2, rs, 2);
    }
    asm volatile("s_barrier" ::: "memory");
    __builtin_amdgcn_s_setprio(1);
#pragma unroll
    for (int mi = 0; mi < 4; ++mi)
#pragma unroll
      for (int nj = 0; nj < 4; ++nj)
        acc[mi][nj] = __builtin_amdgcn_mfma_f32_16x16x32_bf16(
            av[mi], bv[nj], acc[mi][nj], 0, 0, 0);
    __builtin_amdgcn_s_setprio(0);
    asm volatile("s_barrier" ::: "memory");

    // ===== phase 1 (ks = 1) =====
    const int so1 = so0 ^ 32;
#pragma unroll
    for (int mi = 0; mi < 4; ++mi)
      av[mi] =
          __builtin_bit_cast(bf16x8, *(const ushort8*)&Ab[ra + mi * 1024 + so1]);
#pragma unroll
    for (int nj = 0; nj < 4; ++nj)
      bv[nj] =
          __builtin_bit_cast(bf16x8, *(const ushort8*)&Bb[rb + nj * 1024 + so1]);
    if (t < 11) {
      stageA(t + 2, rs, 3);
      stageB(t + 2, rs, 0);
      stageB(t + 2, rs, 1);
    }
    if (t < 11)
      asm volatile("s_waitcnt vmcnt(6)\n\ts_barrier" ::: "memory");
    else if (t == 11)
      asm volatile("s_waitcnt vmcnt(0)\n\ts_barrier" ::: "memory");
    else
      asm volatile("s_barrier" ::: "memory");
    __builtin_amdgcn_s_setprio(1);
#pragma unroll
    for (int mi = 0; mi < 4; ++mi)
#pragma unroll
      for (int nj = 0; nj < 4; ++nj)
        acc[mi][nj] = __builtin_amdgcn_mfma_f32_16x16x32_bf16(
            av[mi], bv[nj], acc[mi][nj], 0, 0, 0);
    __builtin_amdgcn_s_setprio(0);
    asm volatile("s_barrier" ::: "memory");

    rc = rc == 2 ? 0 : rc + 1;
    rs = rs == 2 ? 0 : rs + 1;
  }

  // ---- epilogue: out = acc (hid@W2 + emb) + b2 ----
#pragma unroll
  for (int nj = 0; nj < 4; ++nj) {
    const int cc = n0 + wn + nj * 16 + rl;
    const float bvs = bias[cc];
#pragma unroll
    for (int mi = 0; mi < 4; ++mi) {
      const int rbase = m0 + wm + mi * 16 + ql * 4;
#pragma unroll
      for (int p = 0; p < 4; ++p)
        out[(size_t)(rbase + p) * KD + cc] = acc[mi][nj][p] + bvs;
    }
  }
}

// ---------------------------------------------------------------------------
extern "C" void kernel_launch(void* const* d_in, const int* in_sizes, int n_in,
                              void* d_out, int out_size, void* d_ws,
                              size_t ws_size, hipStream_t stream) {
  const float* x = (const float*)d_in[0];
  const float* cw = (const float*)d_in[1];
  const float* w1 = (const float*)d_in[2];
  const float* b1 = (const float*)d_in[3];
  const float* w2 = (const float*)d_in[4];
  const float* b2 = (const float*)d_in[5];
  float* out = (float*)d_out;

  const size_t M_ALL = 1344 * 128;
  // fixed ws: w2t (768x768), w1ct (768x64), wce (768x64), P (M_ALL x 64)
  const size_t fixed = (size_t)KD * KD * 2 + 2 * (size_t)KD * 64 * 2 +
                       M_ALL * 64 * 2;
  int NC = 2;  // hid (132 MB) stays L3-resident alongside P
  while (NC < 32) {
    size_t cn_ = 1344 / NC;
    size_t need = fixed + cn_ * 128 * (size_t)KD * 2;  // hid only
    if (need <= ws_size) break;
    NC *= 2;
  }
  const int cn = 1344 / NC;
  const int mt = cn / 2;  // 256-row M tiles per chunk

  __hip_bfloat16* w2t = (__hip_bfloat16*)d_ws;
  __hip_bfloat16* w1ct = w2t + (size_t)KD * KD;
  __hip_bfloat16* wce = w1ct + (size_t)KD * 64;
  __hip_bfloat16* Pm = wce + (size_t)KD * 64;
  __hip_bfloat16* hidc = Pm + M_ALL * 64;

  transpose_cvt_kernel<<<576, 256, 0, stream>>>(w2, w2t);
  w1c_kernel<<<dim3(48, 3), 256, 0, stream>>>(cw, w1, w1ct);
  wce_kernel<<<768, 64, 0, stream>>>(cw, wce);
  patchify_kernel<<<1344, 128, 0, stream>>>(x, Pm);

  for (int c = 0; c < NC; ++c) {
    const int nb = c * cn;
    pgemm_kernel<<<dim3(mt, 3), 512, 0, stream>>>(
        Pm + (size_t)nb * 128 * 64, w1ct, b1, hidc);
    gemm2f_kernel<<<dim3(mt * 6), 512, 0, stream>>>(
        hidc, w2t, Pm + (size_t)nb * 128 * 64, wce, b2,
        out + (size_t)nb * 128 * KD, mt);
  }
}